// Round 6
// baseline (385.158 us; speedup 1.0000x reference)
//
#include <hip/hip_runtime.h>

typedef __bf16 bf16x8 __attribute__((ext_vector_type(8)));
typedef float f32x4 __attribute__((ext_vector_type(4)));
typedef __attribute__((address_space(1))) const unsigned char ga_t;
typedef __attribute__((address_space(3))) unsigned char la_t;

static __device__ __forceinline__ unsigned short f2b(float f) {
  union { float f; unsigned int i; } c; c.f = f;
  unsigned int r = c.i + 0x7FFFu + ((c.i >> 16) & 1u);
  return (unsigned short)(r >> 16);
}
static __device__ __forceinline__ unsigned int pack2(float a, float b) {
  return (unsigned int)f2b(a) | ((unsigned int)f2b(b) << 16);
}
static __device__ __forceinline__ int4 ld8f_cvt(const float* __restrict__ p) {
  float4 a = *(const float4*)p;
  float4 b = *(const float4*)(p + 4);
  unsigned short u[8];
  u[0] = f2b(a.x); u[1] = f2b(a.y); u[2] = f2b(a.z); u[3] = f2b(a.w);
  u[4] = f2b(b.x); u[5] = f2b(b.y); u[6] = f2b(b.z); u[7] = f2b(b.w);
  return *(int4*)u;
}
static __device__ __forceinline__ void glds16(const unsigned short* g, unsigned short* l) {
  __builtin_amdgcn_global_load_lds((ga_t*)g, (la_t*)l, 16, 0, 0);
}

// fp32 -> bf16 convert, up to 4 streams via blockIdx.y
__global__ __launch_bounds__(256)
void cvt_z(const float* __restrict__ s0, const float* __restrict__ s1,
           const float* __restrict__ s2, const float* __restrict__ s3,
           unsigned short* d0, unsigned short* d1,
           unsigned short* d2, unsigned short* d3, int n8) {
  const int z = blockIdx.y;
  const float* s = z == 0 ? s0 : z == 1 ? s1 : z == 2 ? s2 : s3;
  unsigned short* d = z == 0 ? d0 : z == 1 ? d1 : z == 2 ? d2 : d3;
  int idx = blockIdx.x * 256 + threadIdx.x;
  if (idx < n8) *(int4*)(d + (size_t)idx * 8) = ld8f_cvt(s + (size_t)idx * 8);
}

// ---------------------------------------------------------------------------
// Shared GEMM core: 128x128 tile, BK=32, global_load_lds width-16 staging
// into UNPADDED 128x32 LDS tiles (lane-linear; glds requires it).
// ---------------------------------------------------------------------------
static __device__ __forceinline__ void gemm_core(
    const unsigned short* __restrict__ A, const unsigned short* __restrict__ W,
    unsigned short* sA, unsigned short* sB, f32x4 acc[4][4],
    int K, int m0, int n0) {
  const int tid = threadIdx.x;
  const int wave = tid >> 6, lane = tid & 63, quad = lane >> 4, l16 = lane & 15;
  const int wrow = (wave >> 1) * 64, wcol = (wave & 1) * 64;
  const int r = tid >> 2, c8 = (tid & 3) * 8;

  const unsigned short* gA0 = A + (size_t)(m0 + r) * K + c8;
  const unsigned short* gA1 = gA0 + (size_t)64 * K;
  const unsigned short* gB0 = W + (size_t)(n0 + r) * K + c8;
  const unsigned short* gB1 = gB0 + (size_t)64 * K;
  unsigned short* lA0 = sA + tid * 8;
  unsigned short* lA1 = lA0 + 2048;
  unsigned short* lB0 = sB + tid * 8;
  unsigned short* lB1 = lB0 + 2048;

  for (int k0 = 0; k0 < K; k0 += 32) {
    __syncthreads();
    glds16(gA0 + k0, lA0);
    glds16(gA1 + k0, lA1);
    glds16(gB0 + k0, lB0);
    glds16(gB1 + k0, lB1);
    __syncthreads();

    bf16x8 af[4], bfv[4];
#pragma unroll
    for (int i = 0; i < 4; ++i)
      af[i] = *(const bf16x8*)(&sA[(wrow + i * 16 + l16) * 32 + quad * 8]);
#pragma unroll
    for (int j = 0; j < 4; ++j)
      bfv[j] = *(const bf16x8*)(&sB[(wcol + j * 16 + l16) * 32 + quad * 8]);
#pragma unroll
    for (int i = 0; i < 4; ++i)
#pragma unroll
      for (int j = 0; j < 4; ++j)
        acc[i][j] = __builtin_amdgcn_mfma_f32_16x16x32_bf16(af[i], bfv[j], acc[i][j], 0, 0, 0);
  }
}

// QKV fused GEMM: z selects projection. z<2 -> bf16 C row-major;
// z==2 -> bf16 C^T (V transposed for attention), via per-wave LDS transpose.
__global__ __launch_bounds__(256, 3)
void gemm_qkv(const unsigned short* __restrict__ A0p, const unsigned short* __restrict__ A1p,
              const unsigned short* __restrict__ A2p,
              const unsigned short* __restrict__ W0p, const unsigned short* __restrict__ W1p,
              const unsigned short* __restrict__ W2p,
              const float* __restrict__ b0p, const float* __restrict__ b1p,
              const float* __restrict__ b2p,
              unsigned short* __restrict__ C0p, unsigned short* __restrict__ C1p,
              unsigned short* __restrict__ C2p,
              int M, int N, int K, int zbase) {
  __shared__ __align__(16) unsigned short smem[8192];  // sA | sB, 16 KB
  const int z = blockIdx.z + zbase;
  const unsigned short* A = z == 0 ? A0p : z == 1 ? A1p : A2p;
  const unsigned short* W = z == 0 ? W0p : z == 1 ? W1p : W2p;
  const float* bias = z == 0 ? b0p : z == 1 ? b1p : b2p;

  const int tid = threadIdx.x;
  const int wave = tid >> 6, lane = tid & 63, quad = lane >> 4, l16 = lane & 15;
  const int m0 = blockIdx.x * 128, n0 = blockIdx.y * 128;
  const int wrow = (wave >> 1) * 64, wcol = (wave & 1) * 64;

  f32x4 acc[4][4];
#pragma unroll
  for (int i = 0; i < 4; ++i)
#pragma unroll
    for (int j = 0; j < 4; ++j) acc[i][j] = (f32x4){0.f, 0.f, 0.f, 0.f};

  gemm_core(A, W, smem, smem + 4096, acc, K, m0, n0);

  if (z < 2) {
    unsigned short* C = z == 0 ? C0p : C1p;
#pragma unroll
    for (int j = 0; j < 4; ++j) {
      const int col = n0 + wcol + j * 16 + l16;
      const float bv = bias[col];
#pragma unroll
      for (int i = 0; i < 4; ++i)
#pragma unroll
        for (int r = 0; r < 4; ++r) {
          const int row = m0 + wrow + i * 16 + quad * 4 + r;
          C[(size_t)row * N + col] = f2b(acc[i][j][r] + bv);
        }
    }
  } else {
    // transpose epilogue: reuse smem (per-wave 16x72 chunk), 4 passes of 16 cols
    __syncthreads();  // all waves done with frag reads before clobbering smem
    unsigned short* sT = smem + wave * 1152;
#pragma unroll
    for (int j = 0; j < 4; ++j) {
      const float bv = bias[n0 + wcol + j * 16 + l16];
#pragma unroll
      for (int i = 0; i < 4; ++i) {
        uint2 pk;
        pk.x = pack2(acc[i][j][0] + bv, acc[i][j][1] + bv);
        pk.y = pack2(acc[i][j][2] + bv, acc[i][j][3] + bv);
        *(uint2*)(&sT[l16 * 72 + i * 16 + quad * 4]) = pk;
      }
      // same-wave LDS write->read (DS in-order within a wave)
#pragma unroll
      for (int t = 0; t < 2; ++t) {
        const int nl = lane >> 2;
        const int colh = (lane & 3) * 8 + t * 32;
        int4 v = *(const int4*)(&sT[nl * 72 + colh]);
        *(int4*)(&C2p[(size_t)(n0 + wcol + j * 16 + nl) * M + m0 + wrow + colh]) = v;
      }
    }
  }
}

// Output GEMM: bf16 A (attn out), bf16 W, fp32 C = d_out
__global__ __launch_bounds__(256, 3)
void gemm_out(const unsigned short* __restrict__ A, const unsigned short* __restrict__ W,
              const float* __restrict__ bias, float* __restrict__ C,
              int M, int N, int K) {
  __shared__ __align__(16) unsigned short smem[8192];
  const int tid = threadIdx.x;
  const int wave = tid >> 6, lane = tid & 63, quad = lane >> 4, l16 = lane & 15;
  const int m0 = blockIdx.x * 128, n0 = blockIdx.y * 128;
  const int wrow = (wave >> 1) * 64, wcol = (wave & 1) * 64;

  f32x4 acc[4][4];
#pragma unroll
  for (int i = 0; i < 4; ++i)
#pragma unroll
    for (int j = 0; j < 4; ++j) acc[i][j] = (f32x4){0.f, 0.f, 0.f, 0.f};

  gemm_core(A, W, smem, smem + 4096, acc, K, m0, n0);

#pragma unroll
  for (int j = 0; j < 4; ++j) {
    const int col = n0 + wcol + j * 16 + l16;
    const float bv = bias[col];
#pragma unroll
    for (int i = 0; i < 4; ++i)
#pragma unroll
      for (int r = 0; r < 4; ++r) {
        const int row = m0 + wrow + i * 16 + quad * 4 + r;
        C[(size_t)row * N + col] = acc[i][j][r] + bv;
      }
  }
}

// ---------------------------------------------------------------------------
// Fused attention v6 = v4 structure with register-pressure fixes:
// 2-wave blocks, 64 q/wave, Q frags from global, register K/V prefetch,
// S^T MFMA order. launch_bounds(128,1) -> up to 256 VGPR (no spills).
// Per-qg S lifetime (8 regs not 32); sP stride 72 -> 36 KB LDS, 4 blocks/CU.
// ---------------------------------------------------------------------------
#define SEQ 2048
#define DMODEL 1024

__global__ __launch_bounds__(128, 1)
void attn_fused(const unsigned short* __restrict__ Q,
                const unsigned short* __restrict__ Km,
                const unsigned short* __restrict__ Vt,   // [1024][4096]
                unsigned short* __restrict__ O) {
  __shared__ __align__(16) unsigned short sK[64 * 72];
  __shared__ __align__(16) unsigned short sVt[64 * 72];
  __shared__ __align__(16) unsigned short sP[2][64 * 72];

  const int tid = threadIdx.x;
  const int wave = tid >> 6, lane = tid & 63, quad = lane >> 4, l16 = lane & 15;
  const int qt = blockIdx.x;        // 0..15
  const int bh = blockIdx.y;        // 0..31
  const int b = bh >> 4, h = bh & 15;
  const size_t qrow0 = (size_t)b * SEQ + qt * 128 + wave * 64;
  const size_t kvrow0 = (size_t)b * SEQ;
  const int hcol = h * 64;
  const int bofs = b * SEQ;

  // Q fragments straight from global (once): 8 int4 gathers
  bf16x8 qa[4][2];
#pragma unroll
  for (int qg = 0; qg < 4; ++qg)
#pragma unroll
    for (int ks = 0; ks < 2; ++ks) {
      int4 v = *(const int4*)(&Q[(qrow0 + qg * 16 + l16) * DMODEL + hcol + ks * 32 + quad * 8]);
      qa[qg][ks] = *(bf16x8*)&v;
    }

  f32x4 acc[4][4];
#pragma unroll
  for (int qg = 0; qg < 4; ++qg)
#pragma unroll
    for (int hg = 0; hg < 4; ++hg) acc[qg][hg] = (f32x4){0.f, 0.f, 0.f, 0.f};
  float lsum[4] = {0.f, 0.f, 0.f, 0.f};

  const float SCL = 0.18033688011112042f;  // log2(e)/sqrt(64)

  // staging geometry: idx = tid + i*128 -> row idx>>3 (0..63), col (idx&7)*8
  const int srow = tid >> 3, scol = (tid & 7) * 8;

  // preload tile 0
  int4 kpre[4], vpre[4];
#pragma unroll
  for (int i = 0; i < 4; ++i) {
    const int rr = srow + i * 16;
    kpre[i] = *(const int4*)(&Km[(kvrow0 + rr) * DMODEL + hcol + scol]);
    vpre[i] = *(const int4*)(&Vt[(size_t)(hcol + rr) * 4096 + bofs + scol]);
  }

  for (int kt = 0; kt < SEQ; kt += 64) {
    __syncthreads();
#pragma unroll
    for (int i = 0; i < 4; ++i) {
      const int rr = srow + i * 16;
      *(int4*)(&sK[rr * 72 + scol]) = kpre[i];
      *(int4*)(&sVt[rr * 72 + scol]) = vpre[i];
    }
    __syncthreads();

    // prefetch next tile (issues now, waited on at next iteration's writes)
    const int ktn = (kt + 64 < SEQ) ? kt + 64 : kt;
#pragma unroll
    for (int i = 0; i < 4; ++i) {
      const int rr = srow + i * 16;
      kpre[i] = *(const int4*)(&Km[(kvrow0 + ktn + rr) * DMODEL + hcol + scol]);
      vpre[i] = *(const int4*)(&Vt[(size_t)(hcol + rr) * 4096 + bofs + ktn + scol]);
    }

#pragma unroll
    for (int kh = 0; kh < 2; ++kh) {     // two 32-key halves
      // K fragments for this half: kb[kg][k-half]
      bf16x8 kb[2][2];
#pragma unroll
      for (int kg = 0; kg < 2; ++kg) {
        const int key16 = kh * 2 + kg;
        kb[kg][0] = *(const bf16x8*)(&sK[(key16 * 16 + l16) * 72 + quad * 8]);
        kb[kg][1] = *(const bf16x8*)(&sK[(key16 * 16 + l16) * 72 + 32 + quad * 8]);
      }
      // per qg: S^T tile -> exp -> packed b64 P-write (short s lifetime)
#pragma unroll
      for (int qg = 0; qg < 4; ++qg) {
        f32x4 s0 = (f32x4){0.f, 0.f, 0.f, 0.f};
        f32x4 s1 = (f32x4){0.f, 0.f, 0.f, 0.f};
        s0 = __builtin_amdgcn_mfma_f32_16x16x32_bf16(kb[0][0], qa[qg][0], s0, 0, 0, 0);
        s0 = __builtin_amdgcn_mfma_f32_16x16x32_bf16(kb[0][1], qa[qg][1], s0, 0, 0, 0);
        s1 = __builtin_amdgcn_mfma_f32_16x16x32_bf16(kb[1][0], qa[qg][0], s1, 0, 0, 0);
        s1 = __builtin_amdgcn_mfma_f32_16x16x32_bf16(kb[1][1], qa[qg][1], s1, 0, 0, 0);
        float p0 = __builtin_amdgcn_exp2f(s0[0] * SCL);
        float p1 = __builtin_amdgcn_exp2f(s0[1] * SCL);
        float p2 = __builtin_amdgcn_exp2f(s0[2] * SCL);
        float p3 = __builtin_amdgcn_exp2f(s0[3] * SCL);
        float p4 = __builtin_amdgcn_exp2f(s1[0] * SCL);
        float p5 = __builtin_amdgcn_exp2f(s1[1] * SCL);
        float p6 = __builtin_amdgcn_exp2f(s1[2] * SCL);
        float p7 = __builtin_amdgcn_exp2f(s1[3] * SCL);
        lsum[qg] += ((p0 + p1) + (p2 + p3)) + ((p4 + p5) + (p6 + p7));
        uint2 pka, pkb;
        pka.x = pack2(p0, p1); pka.y = pack2(p2, p3);
        pkb.x = pack2(p4, p5); pkb.y = pack2(p6, p7);
        *(uint2*)(&sP[wave][(qg * 16 + l16) * 72 + (kh * 2) * 16 + quad * 4]) = pka;
        *(uint2*)(&sP[wave][(qg * 16 + l16) * 72 + (kh * 2 + 1) * 16 + quad * 4]) = pkb;
      }
      // O += P V for this 32-key half (same-wave LDS, in-order)
      bf16x8 vbf[4];
#pragma unroll
      for (int hg = 0; hg < 4; ++hg)
        vbf[hg] = *(const bf16x8*)(&sVt[(hg * 16 + l16) * 72 + kh * 32 + quad * 8]);
#pragma unroll
      for (int qg = 0; qg < 4; ++qg) {
        bf16x8 paf = *(const bf16x8*)(&sP[wave][(qg * 16 + l16) * 72 + kh * 32 + quad * 8]);
#pragma unroll
        for (int hg = 0; hg < 4; ++hg)
          acc[qg][hg] = __builtin_amdgcn_mfma_f32_16x16x32_bf16(paf, vbf[hg], acc[qg][hg], 0, 0, 0);
      }
    }
  }

  // row sums: lane holds partial for q=qg*16+l16 over its quad's keys
#pragma unroll
  for (int qg = 0; qg < 4; ++qg) {
    float v = lsum[qg];
    v += __shfl_xor(v, 16, 64);
    v += __shfl_xor(v, 32, 64);
    lsum[qg] = v;
  }
#pragma unroll
  for (int qg = 0; qg < 4; ++qg)
#pragma unroll
    for (int r = 0; r < 4; ++r) {
      const float linv = 1.0f / __shfl(lsum[qg], quad * 4 + r, 64);
      const size_t row = qrow0 + qg * 16 + quad * 4 + r;
#pragma unroll
      for (int hg = 0; hg < 4; ++hg)
        O[row * DMODEL + hcol + hg * 16 + l16] = f2b(acc[qg][hg][r] * linv);
    }
}

// ---------------------------------------------------------------------------
extern "C" void kernel_launch(void* const* d_in, const int* in_sizes, int n_in,
                              void* d_out, int out_size, void* d_ws, size_t ws_size,
                              hipStream_t stream) {
  const float* xq = (const float*)d_in[0];
  const float* xv = (const float*)d_in[1];
  const float* xk = (const float*)d_in[2];
  const float* Wq = (const float*)d_in[3];
  const float* bq = (const float*)d_in[4];
  const float* Wk = (const float*)d_in[5];
  const float* bk = (const float*)d_in[6];
  const float* Wv = (const float*)d_in[7];
  const float* bv = (const float*)d_in[8];
  const float* Wo = (const float*)d_in[9];
  const float* bo = (const float*)d_in[10];
  float* out = (float*)d_out;

  const int S = 2048, D = 1024, M = 4096;
  const size_t MD = (size_t)M * D, DD = (size_t)D * D;
  unsigned short* P = (unsigned short*)d_ws;
  dim3 bb(256);
  dim3 gg(M / 128, D / 128);

  const size_t need = (3 * MD + 4 * DD + 3 * MD) * 2;
  if (ws_size >= need) {
    // fused path: all QKV in one z=3 launch (768 blocks = 3/CU)
    unsigned short* Ab = P;            // 3 act slices
    unsigned short* Wb = Ab + 3 * MD;  // 4 weight slices (q,k,v,o)
    unsigned short* Qw = Wb + 4 * DD;
    unsigned short* Kw = Qw + MD;
    unsigned short* Vtw = Kw + MD;
    unsigned short* Ao = Ab;           // attn out reuses act slice 0

    cvt_z<<<dim3((int)(MD / 8 / 256), 3), bb, 0, stream>>>(
        xq, xk, xv, xq, Ab, Ab + MD, Ab + 2 * MD, Ab, (int)(MD / 8));
    cvt_z<<<dim3((int)(DD / 8 / 256), 4), bb, 0, stream>>>(
        Wq, Wk, Wv, Wo, Wb, Wb + DD, Wb + 2 * DD, Wb + 3 * DD, (int)(DD / 8));
    gemm_qkv<<<dim3(M / 128, D / 128, 3), bb, 0, stream>>>(
        Ab, Ab + MD, Ab + 2 * MD, Wb, Wb + DD, Wb + 2 * DD,
        bq, bk, bv, Qw, Kw, Vtw, M, D, D, 0);
    attn_fused<<<dim3(S / 128, 32), dim3(128), 0, stream>>>(Qw, Kw, Vtw, Ao);
    gemm_out<<<gg, bb, 0, stream>>>(Ao, Wb + 3 * DD, bo, out, M, D, D);
  } else {
    // sequential fallback (34 MB): act 8MB | W 2MB | Q 8 | K 8 | Vt 8
    unsigned short* Ab = P;
    unsigned short* Wb = Ab + MD;
    unsigned short* Qw = Wb + DD;
    unsigned short* Kw = Qw + MD;
    unsigned short* Vtw = Kw + MD;
    unsigned short* Ao = Ab;
    const int an = (int)(MD / 8), wn = (int)(DD / 8);

    cvt_z<<<dim3(an / 256, 1), bb, 0, stream>>>(xq, xq, xq, xq, Ab, Ab, Ab, Ab, an);
    cvt_z<<<dim3(wn / 256, 1), bb, 0, stream>>>(Wq, Wq, Wq, Wq, Wb, Wb, Wb, Wb, wn);
    gemm_qkv<<<dim3(M / 128, D / 128, 1), bb, 0, stream>>>(
        Ab, Ab, Ab, Wb, Wb, Wb, bq, bq, bq, Qw, Qw, Qw, M, D, D, 0);

    cvt_z<<<dim3(an / 256, 1), bb, 0, stream>>>(xk, xk, xk, xk, Ab, Ab, Ab, Ab, an);
    cvt_z<<<dim3(wn / 256, 1), bb, 0, stream>>>(Wk, Wk, Wk, Wk, Wb, Wb, Wb, Wb, wn);
    gemm_qkv<<<dim3(M / 128, D / 128, 1), bb, 0, stream>>>(
        Ab, Ab, Ab, Wb, Wb, Wb, bk, bk, bk, Kw, Kw, Kw, M, D, D, 0);

    cvt_z<<<dim3(an / 256, 1), bb, 0, stream>>>(xv, xv, xv, xv, Ab, Ab, Ab, Ab, an);
    cvt_z<<<dim3(wn / 256, 1), bb, 0, stream>>>(Wv, Wv, Wv, Wv, Wb, Wb, Wb, Wb, wn);
    gemm_qkv<<<dim3(M / 128, D / 128, 1), bb, 0, stream>>>(
        Ab, Ab, Ab, Wb, Wb, Wb, bv, bv, bv, Vtw, Vtw, Vtw, M, D, D, 2);

    attn_fused<<<dim3(S / 128, 32), dim3(128), 0, stream>>>(Qw, Kw, Vtw, Ao);

    cvt_z<<<dim3(wn / 256, 1), bb, 0, stream>>>(Wo, Wo, Wo, Wo, Wb, Wb, Wb, Wb, wn);
    gemm_out<<<gg, bb, 0, stream>>>(Ao, Wb, bo, out, M, D, D);
  }
}

// Round 7
// 253.297 us; speedup vs baseline: 1.5206x; 1.5206x over previous
//
#include <hip/hip_runtime.h>

typedef __bf16 bf16x8 __attribute__((ext_vector_type(8)));
typedef float f32x4 __attribute__((ext_vector_type(4)));
typedef __attribute__((address_space(1))) const unsigned char ga_t;
typedef __attribute__((address_space(3))) unsigned char la_t;

static __device__ __forceinline__ unsigned short f2b(float f) {
  union { float f; unsigned int i; } c; c.f = f;
  unsigned int r = c.i + 0x7FFFu + ((c.i >> 16) & 1u);
  return (unsigned short)(r >> 16);
}
static __device__ __forceinline__ unsigned int pack2(float a, float b) {
  return (unsigned int)f2b(a) | ((unsigned int)f2b(b) << 16);
}
static __device__ __forceinline__ int4 ld8f_cvt(const float* __restrict__ p) {
  float4 a = *(const float4*)p;
  float4 b = *(const float4*)(p + 4);
  unsigned short u[8];
  u[0] = f2b(a.x); u[1] = f2b(a.y); u[2] = f2b(a.z); u[3] = f2b(a.w);
  u[4] = f2b(b.x); u[5] = f2b(b.y); u[6] = f2b(b.z); u[7] = f2b(b.w);
  return *(int4*)u;
}
static __device__ __forceinline__ void glds16(const unsigned short* g, unsigned short* l) {
  __builtin_amdgcn_global_load_lds((ga_t*)g, (la_t*)l, 16, 0, 0);
}

// fp32 -> bf16 convert, up to 4 streams via blockIdx.y
__global__ __launch_bounds__(256)
void cvt_z(const float* __restrict__ s0, const float* __restrict__ s1,
           const float* __restrict__ s2, const float* __restrict__ s3,
           unsigned short* d0, unsigned short* d1,
           unsigned short* d2, unsigned short* d3, int n8) {
  const int z = blockIdx.y;
  const float* s = z == 0 ? s0 : z == 1 ? s1 : z == 2 ? s2 : s3;
  unsigned short* d = z == 0 ? d0 : z == 1 ? d1 : z == 2 ? d2 : d3;
  int idx = blockIdx.x * 256 + threadIdx.x;
  if (idx < n8) *(int4*)(d + (size_t)idx * 8) = ld8f_cvt(s + (size_t)idx * 8);
}

// ---------------------------------------------------------------------------
// Shared GEMM core: 128x128 tile, BK=32, global_load_lds width-16 staging
// into UNPADDED 128x32 LDS tiles (lane-linear; glds requires it).
// ---------------------------------------------------------------------------
static __device__ __forceinline__ void gemm_core(
    const unsigned short* __restrict__ A, const unsigned short* __restrict__ W,
    unsigned short* sA, unsigned short* sB, f32x4 acc[4][4],
    int K, int m0, int n0) {
  const int tid = threadIdx.x;
  const int wave = tid >> 6, lane = tid & 63, quad = lane >> 4, l16 = lane & 15;
  const int wrow = (wave >> 1) * 64, wcol = (wave & 1) * 64;
  const int r = tid >> 2, c8 = (tid & 3) * 8;

  const unsigned short* gA0 = A + (size_t)(m0 + r) * K + c8;
  const unsigned short* gA1 = gA0 + (size_t)64 * K;
  const unsigned short* gB0 = W + (size_t)(n0 + r) * K + c8;
  const unsigned short* gB1 = gB0 + (size_t)64 * K;
  unsigned short* lA0 = sA + tid * 8;
  unsigned short* lA1 = lA0 + 2048;
  unsigned short* lB0 = sB + tid * 8;
  unsigned short* lB1 = lB0 + 2048;

  for (int k0 = 0; k0 < K; k0 += 32) {
    __syncthreads();
    glds16(gA0 + k0, lA0);
    glds16(gA1 + k0, lA1);
    glds16(gB0 + k0, lB0);
    glds16(gB1 + k0, lB1);
    __syncthreads();

    bf16x8 af[4], bfv[4];
#pragma unroll
    for (int i = 0; i < 4; ++i)
      af[i] = *(const bf16x8*)(&sA[(wrow + i * 16 + l16) * 32 + quad * 8]);
#pragma unroll
    for (int j = 0; j < 4; ++j)
      bfv[j] = *(const bf16x8*)(&sB[(wcol + j * 16 + l16) * 32 + quad * 8]);
#pragma unroll
    for (int i = 0; i < 4; ++i)
#pragma unroll
      for (int j = 0; j < 4; ++j)
        acc[i][j] = __builtin_amdgcn_mfma_f32_16x16x32_bf16(af[i], bfv[j], acc[i][j], 0, 0, 0);
  }
}

// QKV fused GEMM: z selects projection. z<2 -> bf16 C row-major;
// z==2 -> bf16 C^T (V transposed for attention), via per-wave LDS transpose.
__global__ __launch_bounds__(256, 3)
void gemm_qkv(const unsigned short* __restrict__ A0p, const unsigned short* __restrict__ A1p,
              const unsigned short* __restrict__ A2p,
              const unsigned short* __restrict__ W0p, const unsigned short* __restrict__ W1p,
              const unsigned short* __restrict__ W2p,
              const float* __restrict__ b0p, const float* __restrict__ b1p,
              const float* __restrict__ b2p,
              unsigned short* __restrict__ C0p, unsigned short* __restrict__ C1p,
              unsigned short* __restrict__ C2p,
              int M, int N, int K, int zbase) {
  __shared__ __align__(16) unsigned short smem[8192];  // sA | sB, 16 KB
  const int z = blockIdx.z + zbase;
  const unsigned short* A = z == 0 ? A0p : z == 1 ? A1p : A2p;
  const unsigned short* W = z == 0 ? W0p : z == 1 ? W1p : W2p;
  const float* bias = z == 0 ? b0p : z == 1 ? b1p : b2p;

  const int tid = threadIdx.x;
  const int wave = tid >> 6, lane = tid & 63, quad = lane >> 4, l16 = lane & 15;
  const int m0 = blockIdx.x * 128, n0 = blockIdx.y * 128;
  const int wrow = (wave >> 1) * 64, wcol = (wave & 1) * 64;

  f32x4 acc[4][4];
#pragma unroll
  for (int i = 0; i < 4; ++i)
#pragma unroll
    for (int j = 0; j < 4; ++j) acc[i][j] = (f32x4){0.f, 0.f, 0.f, 0.f};

  gemm_core(A, W, smem, smem + 4096, acc, K, m0, n0);

  if (z < 2) {
    unsigned short* C = z == 0 ? C0p : C1p;
#pragma unroll
    for (int j = 0; j < 4; ++j) {
      const int col = n0 + wcol + j * 16 + l16;
      const float bv = bias[col];
#pragma unroll
      for (int i = 0; i < 4; ++i)
#pragma unroll
        for (int r = 0; r < 4; ++r) {
          const int row = m0 + wrow + i * 16 + quad * 4 + r;
          C[(size_t)row * N + col] = f2b(acc[i][j][r] + bv);
        }
    }
  } else {
    // transpose epilogue: reuse smem (per-wave 16x72 chunk), 4 passes of 16 cols
    __syncthreads();  // all waves done with frag reads before clobbering smem
    unsigned short* sT = smem + wave * 1152;
#pragma unroll
    for (int j = 0; j < 4; ++j) {
      const float bv = bias[n0 + wcol + j * 16 + l16];
#pragma unroll
      for (int i = 0; i < 4; ++i) {
        uint2 pk;
        pk.x = pack2(acc[i][j][0] + bv, acc[i][j][1] + bv);
        pk.y = pack2(acc[i][j][2] + bv, acc[i][j][3] + bv);
        *(uint2*)(&sT[l16 * 72 + i * 16 + quad * 4]) = pk;
      }
      // same-wave LDS write->read (DS in-order within a wave)
#pragma unroll
      for (int t = 0; t < 2; ++t) {
        const int nl = lane >> 2;
        const int colh = (lane & 3) * 8 + t * 32;
        int4 v = *(const int4*)(&sT[nl * 72 + colh]);
        *(int4*)(&C2p[(size_t)(n0 + wcol + j * 16 + nl) * M + m0 + wrow + colh]) = v;
      }
    }
  }
}

// Output GEMM: bf16 A (attn out), bf16 W, fp32 C = d_out
__global__ __launch_bounds__(256, 3)
void gemm_out(const unsigned short* __restrict__ A, const unsigned short* __restrict__ W,
              const float* __restrict__ bias, float* __restrict__ C,
              int M, int N, int K) {
  __shared__ __align__(16) unsigned short smem[8192];
  const int tid = threadIdx.x;
  const int wave = tid >> 6, lane = tid & 63, quad = lane >> 4, l16 = lane & 15;
  const int m0 = blockIdx.x * 128, n0 = blockIdx.y * 128;
  const int wrow = (wave >> 1) * 64, wcol = (wave & 1) * 64;

  f32x4 acc[4][4];
#pragma unroll
  for (int i = 0; i < 4; ++i)
#pragma unroll
    for (int j = 0; j < 4; ++j) acc[i][j] = (f32x4){0.f, 0.f, 0.f, 0.f};

  gemm_core(A, W, smem, smem + 4096, acc, K, m0, n0);

#pragma unroll
  for (int j = 0; j < 4; ++j) {
    const int col = n0 + wcol + j * 16 + l16;
    const float bv = bias[col];
#pragma unroll
    for (int i = 0; i < 4; ++i)
#pragma unroll
      for (int r = 0; r < 4; ++r) {
        const int row = m0 + wrow + i * 16 + quad * 4 + r;
        C[(size_t)row * N + col] = acc[i][j][r] + bv;
      }
  }
}

// ---------------------------------------------------------------------------
// Fused attention v7 = R4's v3 (known-good 71 us) + sQ/sP LDS union.
// Block = 128 q rows of one (b,h); 4 waves x 32 q; 64-key tiles; V^T global.
// sQ (prologue-only, 18 KB) and sP (loop-only, 18 KB) share one buffer:
// sP writes happen after the loop's first __syncthreads(), which
// happens-after all qa reads (compiler drains lgkmcnt before s_barrier).
// 36 KB LDS -> 4 blocks/CU (was 54 KB -> 2).
// ---------------------------------------------------------------------------
#define SEQ 2048
#define DMODEL 1024

__global__ __launch_bounds__(256, 2)
void attn_fused(const unsigned short* __restrict__ Q,
                const unsigned short* __restrict__ Km,
                const unsigned short* __restrict__ Vt,   // [1024][4096]
                unsigned short* __restrict__ O) {
  __shared__ __align__(16) unsigned short sU[128 * 72];   // sQ / sP union
  __shared__ __align__(16) unsigned short sK[64 * 72];
  __shared__ __align__(16) unsigned short sVt[64 * 72];

  const int tid = threadIdx.x;
  const int wave = tid >> 6, lane = tid & 63, quad = lane >> 4, l16 = lane & 15;
  const int qt = blockIdx.x;        // 0..15
  const int bh = blockIdx.y;        // 0..31
  const int b = bh >> 4, h = bh & 15;
  const size_t qrow0 = (size_t)b * SEQ + qt * 128;
  const size_t kvrow0 = (size_t)b * SEQ;
  const int hcol = h * 64;
  const int bofs = b * SEQ;

  // stage Q tile 128x64 into sU
#pragma unroll
  for (int i = 0; i < 4; ++i) {
    const int idx = tid + i * 256;
    const int r = idx >> 3, c = (idx & 7) * 8;
    *(int4*)(&sU[r * 72 + c]) = *(const int4*)(&Q[(qrow0 + r) * DMODEL + hcol + c]);
  }
  __syncthreads();

  const int qw = wave * 32;
  bf16x8 qa[2][2];
#pragma unroll
  for (int qi = 0; qi < 2; ++qi)
#pragma unroll
    for (int ks = 0; ks < 2; ++ks)
      qa[qi][ks] = *(const bf16x8*)(&sU[(qw + qi * 16 + l16) * 72 + ks * 32 + quad * 8]);

  // per-wave sP slice overlays exactly the sQ rows this wave consumed
  unsigned short* sP = sU + wave * (32 * 72);

  f32x4 acc[2][4];
#pragma unroll
  for (int qi = 0; qi < 2; ++qi)
#pragma unroll
    for (int hg = 0; hg < 4; ++hg) acc[qi][hg] = (f32x4){0.f, 0.f, 0.f, 0.f};
  float lsum[2] = {0.f, 0.f};

  const float SCL = 0.18033688011112042f;  // log2(e)/sqrt(64)
  const int sr = tid >> 3, sc = (tid & 7) * 8;

  for (int kt = 0; kt < SEQ; kt += 64) {
    __syncthreads();
    {
      const int idx2 = tid + 256;
      const int r2 = idx2 >> 3, c2 = (idx2 & 7) * 8;
      *(int4*)(&sK[sr * 72 + sc]) = *(const int4*)(&Km[(kvrow0 + kt + sr) * DMODEL + hcol + sc]);
      *(int4*)(&sK[r2 * 72 + c2]) = *(const int4*)(&Km[(kvrow0 + kt + r2) * DMODEL + hcol + c2]);
      *(int4*)(&sVt[sr * 72 + sc]) = *(const int4*)(&Vt[(size_t)(hcol + sr) * 4096 + bofs + kt + sc]);
      *(int4*)(&sVt[r2 * 72 + c2]) = *(const int4*)(&Vt[(size_t)(hcol + r2) * 4096 + bofs + kt + c2]);
    }
    __syncthreads();

    // S^T[key][q] = mfma(A=K rows, B=Q rows): row=key(quad*4+r), col=q(l16)
    f32x4 s[2][4];
#pragma unroll
    for (int qi = 0; qi < 2; ++qi)
#pragma unroll
      for (int kg = 0; kg < 4; ++kg) s[qi][kg] = (f32x4){0.f, 0.f, 0.f, 0.f};
#pragma unroll
    for (int kg = 0; kg < 4; ++kg) {
      bf16x8 kb0 = *(const bf16x8*)(&sK[(kg * 16 + l16) * 72 + quad * 8]);
      bf16x8 kb1 = *(const bf16x8*)(&sK[(kg * 16 + l16) * 72 + 32 + quad * 8]);
#pragma unroll
      for (int qi = 0; qi < 2; ++qi) {
        s[qi][kg] = __builtin_amdgcn_mfma_f32_16x16x32_bf16(kb0, qa[qi][0], s[qi][kg], 0, 0, 0);
        s[qi][kg] = __builtin_amdgcn_mfma_f32_16x16x32_bf16(kb1, qa[qi][1], s[qi][kg], 0, 0, 0);
      }
    }

    // exp (un-shifted), pack 4 consecutive keys -> one b64 write into q-major sP
#pragma unroll
    for (int qi = 0; qi < 2; ++qi)
#pragma unroll
      for (int kg = 0; kg < 4; ++kg) {
        float p0 = __builtin_amdgcn_exp2f(s[qi][kg][0] * SCL);
        float p1 = __builtin_amdgcn_exp2f(s[qi][kg][1] * SCL);
        float p2 = __builtin_amdgcn_exp2f(s[qi][kg][2] * SCL);
        float p3 = __builtin_amdgcn_exp2f(s[qi][kg][3] * SCL);
        lsum[qi] += (p0 + p1) + (p2 + p3);
        uint2 pk; pk.x = pack2(p0, p1); pk.y = pack2(p2, p3);
        *(uint2*)(&sP[(qi * 16 + l16) * 72 + kg * 16 + quad * 4]) = pk;
      }

    // O += P V  (same-wave LDS write->read, in-order)
#pragma unroll
    for (int ks = 0; ks < 2; ++ks) {
      bf16x8 pa[2], vb[4];
#pragma unroll
      for (int qi = 0; qi < 2; ++qi)
        pa[qi] = *(const bf16x8*)(&sP[(qi * 16 + l16) * 72 + ks * 32 + quad * 8]);
#pragma unroll
      for (int hg = 0; hg < 4; ++hg)
        vb[hg] = *(const bf16x8*)(&sVt[(hg * 16 + l16) * 72 + ks * 32 + quad * 8]);
#pragma unroll
      for (int qi = 0; qi < 2; ++qi)
#pragma unroll
        for (int hg = 0; hg < 4; ++hg)
          acc[qi][hg] = __builtin_amdgcn_mfma_f32_16x16x32_bf16(pa[qi], vb[hg], acc[qi][hg], 0, 0, 0);
    }
  }

  // row-sum: lane holds sum for q = qi*16+l16 over its quad's keys; reduce quads
#pragma unroll
  for (int qi = 0; qi < 2; ++qi) {
    float v = lsum[qi];
    v += __shfl_xor(v, 16, 64);
    v += __shfl_xor(v, 32, 64);
    lsum[qi] = v;
  }
  float linv[2][4];
#pragma unroll
  for (int qi = 0; qi < 2; ++qi)
#pragma unroll
    for (int r = 0; r < 4; ++r)
      linv[qi][r] = 1.0f / __shfl(lsum[qi], quad * 4 + r, 64);

#pragma unroll
  for (int qi = 0; qi < 2; ++qi)
#pragma unroll
    for (int hg = 0; hg < 4; ++hg)
#pragma unroll
      for (int r = 0; r < 4; ++r) {
        const size_t row = qrow0 + qw + qi * 16 + quad * 4 + r;
        O[row * DMODEL + hcol + hg * 16 + l16] = f2b(acc[qi][hg][r] * linv[qi][r]);
      }
}

// ---------------------------------------------------------------------------
extern "C" void kernel_launch(void* const* d_in, const int* in_sizes, int n_in,
                              void* d_out, int out_size, void* d_ws, size_t ws_size,
                              hipStream_t stream) {
  const float* xq = (const float*)d_in[0];
  const float* xv = (const float*)d_in[1];
  const float* xk = (const float*)d_in[2];
  const float* Wq = (const float*)d_in[3];
  const float* bq = (const float*)d_in[4];
  const float* Wk = (const float*)d_in[5];
  const float* bk = (const float*)d_in[6];
  const float* Wv = (const float*)d_in[7];
  const float* bv = (const float*)d_in[8];
  const float* Wo = (const float*)d_in[9];
  const float* bo = (const float*)d_in[10];
  float* out = (float*)d_out;

  const int S = 2048, D = 1024, M = 4096;
  const size_t MD = (size_t)M * D, DD = (size_t)D * D;
  unsigned short* P = (unsigned short*)d_ws;
  dim3 bb(256);
  dim3 gg(M / 128, D / 128);

  const size_t need = (3 * MD + 4 * DD + 3 * MD) * 2;
  if (ws_size >= need) {
    // fused path: all QKV in one z=3 launch (768 blocks = 3/CU)
    unsigned short* Ab = P;            // 3 act slices
    unsigned short* Wb = Ab + 3 * MD;  // 4 weight slices (q,k,v,o)
    unsigned short* Qw = Wb + 4 * DD;
    unsigned short* Kw = Qw + MD;
    unsigned short* Vtw = Kw + MD;
    unsigned short* Ao = Ab;           // attn out reuses act slice 0

    cvt_z<<<dim3((int)(MD / 8 / 256), 3), bb, 0, stream>>>(
        xq, xk, xv, xq, Ab, Ab + MD, Ab + 2 * MD, Ab, (int)(MD / 8));
    cvt_z<<<dim3((int)(DD / 8 / 256), 4), bb, 0, stream>>>(
        Wq, Wk, Wv, Wo, Wb, Wb + DD, Wb + 2 * DD, Wb + 3 * DD, (int)(DD / 8));
    gemm_qkv<<<dim3(M / 128, D / 128, 3), bb, 0, stream>>>(
        Ab, Ab + MD, Ab + 2 * MD, Wb, Wb + DD, Wb + 2 * DD,
        bq, bk, bv, Qw, Kw, Vtw, M, D, D, 0);
    attn_fused<<<dim3(S / 128, 32), bb, 0, stream>>>(Qw, Kw, Vtw, Ao);
    gemm_out<<<gg, bb, 0, stream>>>(Ao, Wb + 3 * DD, bo, out, M, D, D);
  } else {
    // sequential fallback (34 MB): act 8MB | W 2MB | Q 8 | K 8 | Vt 8
    unsigned short* Ab = P;
    unsigned short* Wb = Ab + MD;
    unsigned short* Qw = Wb + DD;
    unsigned short* Kw = Qw + MD;
    unsigned short* Vtw = Kw + MD;
    unsigned short* Ao = Ab;
    const int an = (int)(MD / 8), wn = (int)(DD / 8);

    cvt_z<<<dim3(an / 256, 1), bb, 0, stream>>>(xq, xq, xq, xq, Ab, Ab, Ab, Ab, an);
    cvt_z<<<dim3(wn / 256, 1), bb, 0, stream>>>(Wq, Wq, Wq, Wq, Wb, Wb, Wb, Wb, wn);
    gemm_qkv<<<dim3(M / 128, D / 128, 1), bb, 0, stream>>>(
        Ab, Ab, Ab, Wb, Wb, Wb, bq, bq, bq, Qw, Qw, Qw, M, D, D, 0);

    cvt_z<<<dim3(an / 256, 1), bb, 0, stream>>>(xk, xk, xk, xk, Ab, Ab, Ab, Ab, an);
    cvt_z<<<dim3(wn / 256, 1), bb, 0, stream>>>(Wk, Wk, Wk, Wk, Wb, Wb, Wb, Wb, wn);
    gemm_qkv<<<dim3(M / 128, D / 128, 1), bb, 0, stream>>>(
        Ab, Ab, Ab, Wb, Wb, Wb, bk, bk, bk, Kw, Kw, Kw, M, D, D, 0);

    cvt_z<<<dim3(an / 256, 1), bb, 0, stream>>>(xv, xv, xv, xv, Ab, Ab, Ab, Ab, an);
    cvt_z<<<dim3(wn / 256, 1), bb, 0, stream>>>(Wv, Wv, Wv, Wv, Wb, Wb, Wb, Wb, wn);
    gemm_qkv<<<dim3(M / 128, D / 128, 1), bb, 0, stream>>>(
        Ab, Ab, Ab, Wb, Wb, Wb, bv, bv, bv, Vtw, Vtw, Vtw, M, D, D, 2);

    attn_fused<<<dim3(S / 128, 32), bb, 0, stream>>>(Qw, Kw, Vtw, Ao);

    cvt_z<<<dim3(wn / 256, 1), bb, 0, stream>>>(Wo, Wo, Wo, Wo, Wb, Wb, Wb, Wb, wn);
    gemm_out<<<gg, bb, 0, stream>>>(Ao, Wb, bo, out, M, D, D);
  }
}

// Round 8
// 242.198 us; speedup vs baseline: 1.5903x; 1.0458x over previous
//
#include <hip/hip_runtime.h>

typedef __bf16 bf16x8 __attribute__((ext_vector_type(8)));
typedef float f32x4 __attribute__((ext_vector_type(4)));
typedef __attribute__((address_space(1))) const unsigned char ga_t;
typedef __attribute__((address_space(3))) unsigned char la_t;

static __device__ __forceinline__ unsigned short f2b(float f) {
  union { float f; unsigned int i; } c; c.f = f;
  unsigned int r = c.i + 0x7FFFu + ((c.i >> 16) & 1u);
  return (unsigned short)(r >> 16);
}
static __device__ __forceinline__ unsigned int pack2(float a, float b) {
  return (unsigned int)f2b(a) | ((unsigned int)f2b(b) << 16);
}
static __device__ __forceinline__ int4 ld8f_cvt(const float* __restrict__ p) {
  float4 a = *(const float4*)p;
  float4 b = *(const float4*)(p + 4);
  unsigned short u[8];
  u[0] = f2b(a.x); u[1] = f2b(a.y); u[2] = f2b(a.z); u[3] = f2b(a.w);
  u[4] = f2b(b.x); u[5] = f2b(b.y); u[6] = f2b(b.z); u[7] = f2b(b.w);
  return *(int4*)u;
}
static __device__ __forceinline__ void glds16(const unsigned short* g, unsigned short* l) {
  __builtin_amdgcn_global_load_lds((ga_t*)g, (la_t*)l, 16, 0, 0);
}

// fp32 -> bf16 convert, up to 4 streams via blockIdx.y
__global__ __launch_bounds__(256)
void cvt_z(const float* __restrict__ s0, const float* __restrict__ s1,
           const float* __restrict__ s2, const float* __restrict__ s3,
           unsigned short* d0, unsigned short* d1,
           unsigned short* d2, unsigned short* d3, int n8) {
  const int z = blockIdx.y;
  const float* s = z == 0 ? s0 : z == 1 ? s1 : z == 2 ? s2 : s3;
  unsigned short* d = z == 0 ? d0 : z == 1 ? d1 : z == 2 ? d2 : d3;
  int idx = blockIdx.x * 256 + threadIdx.x;
  if (idx < n8) *(int4*)(d + (size_t)idx * 8) = ld8f_cvt(s + (size_t)idx * 8);
}

// ---------------------------------------------------------------------------
// Shared GEMM core: 128x128 tile, BK=32, global_load_lds width-16 staging
// into UNPADDED 128x32 LDS tiles (lane-linear; glds requires it).
// ---------------------------------------------------------------------------
static __device__ __forceinline__ void gemm_core(
    const unsigned short* __restrict__ A, const unsigned short* __restrict__ W,
    unsigned short* sA, unsigned short* sB, f32x4 acc[4][4],
    int K, int m0, int n0) {
  const int tid = threadIdx.x;
  const int wave = tid >> 6, lane = tid & 63, quad = lane >> 4, l16 = lane & 15;
  const int wrow = (wave >> 1) * 64, wcol = (wave & 1) * 64;
  const int r = tid >> 2, c8 = (tid & 3) * 8;

  const unsigned short* gA0 = A + (size_t)(m0 + r) * K + c8;
  const unsigned short* gA1 = gA0 + (size_t)64 * K;
  const unsigned short* gB0 = W + (size_t)(n0 + r) * K + c8;
  const unsigned short* gB1 = gB0 + (size_t)64 * K;
  unsigned short* lA0 = sA + tid * 8;
  unsigned short* lA1 = lA0 + 2048;
  unsigned short* lB0 = sB + tid * 8;
  unsigned short* lB1 = lB0 + 2048;

  for (int k0 = 0; k0 < K; k0 += 32) {
    __syncthreads();
    glds16(gA0 + k0, lA0);
    glds16(gA1 + k0, lA1);
    glds16(gB0 + k0, lB0);
    glds16(gB1 + k0, lB1);
    __syncthreads();

    bf16x8 af[4], bfv[4];
#pragma unroll
    for (int i = 0; i < 4; ++i)
      af[i] = *(const bf16x8*)(&sA[(wrow + i * 16 + l16) * 32 + quad * 8]);
#pragma unroll
    for (int j = 0; j < 4; ++j)
      bfv[j] = *(const bf16x8*)(&sB[(wcol + j * 16 + l16) * 32 + quad * 8]);
#pragma unroll
    for (int i = 0; i < 4; ++i)
#pragma unroll
      for (int j = 0; j < 4; ++j)
        acc[i][j] = __builtin_amdgcn_mfma_f32_16x16x32_bf16(af[i], bfv[j], acc[i][j], 0, 0, 0);
  }
}

// QKV fused GEMM: z selects projection. z<2 -> bf16 C row-major;
// z==2 -> bf16 C^T (V transposed for attention), via per-wave LDS transpose.
__global__ __launch_bounds__(256, 3)
void gemm_qkv(const unsigned short* __restrict__ A0p, const unsigned short* __restrict__ A1p,
              const unsigned short* __restrict__ A2p,
              const unsigned short* __restrict__ W0p, const unsigned short* __restrict__ W1p,
              const unsigned short* __restrict__ W2p,
              const float* __restrict__ b0p, const float* __restrict__ b1p,
              const float* __restrict__ b2p,
              unsigned short* __restrict__ C0p, unsigned short* __restrict__ C1p,
              unsigned short* __restrict__ C2p,
              int M, int N, int K, int zbase) {
  __shared__ __align__(16) unsigned short smem[8192];  // sA | sB, 16 KB
  const int z = blockIdx.z + zbase;
  const unsigned short* A = z == 0 ? A0p : z == 1 ? A1p : A2p;
  const unsigned short* W = z == 0 ? W0p : z == 1 ? W1p : W2p;
  const float* bias = z == 0 ? b0p : z == 1 ? b1p : b2p;

  const int tid = threadIdx.x;
  const int wave = tid >> 6, lane = tid & 63, quad = lane >> 4, l16 = lane & 15;
  const int m0 = blockIdx.x * 128, n0 = blockIdx.y * 128;
  const int wrow = (wave >> 1) * 64, wcol = (wave & 1) * 64;

  f32x4 acc[4][4];
#pragma unroll
  for (int i = 0; i < 4; ++i)
#pragma unroll
    for (int j = 0; j < 4; ++j) acc[i][j] = (f32x4){0.f, 0.f, 0.f, 0.f};

  gemm_core(A, W, smem, smem + 4096, acc, K, m0, n0);

  if (z < 2) {
    unsigned short* C = z == 0 ? C0p : C1p;
#pragma unroll
    for (int j = 0; j < 4; ++j) {
      const int col = n0 + wcol + j * 16 + l16;
      const float bv = bias[col];
#pragma unroll
      for (int i = 0; i < 4; ++i)
#pragma unroll
        for (int r = 0; r < 4; ++r) {
          const int row = m0 + wrow + i * 16 + quad * 4 + r;
          C[(size_t)row * N + col] = f2b(acc[i][j][r] + bv);
        }
    }
  } else {
    // transpose epilogue: reuse smem (per-wave 16x72 chunk), 4 passes of 16 cols
    __syncthreads();  // all waves done with frag reads before clobbering smem
    unsigned short* sT = smem + wave * 1152;
#pragma unroll
    for (int j = 0; j < 4; ++j) {
      const float bv = bias[n0 + wcol + j * 16 + l16];
#pragma unroll
      for (int i = 0; i < 4; ++i) {
        uint2 pk;
        pk.x = pack2(acc[i][j][0] + bv, acc[i][j][1] + bv);
        pk.y = pack2(acc[i][j][2] + bv, acc[i][j][3] + bv);
        *(uint2*)(&sT[l16 * 72 + i * 16 + quad * 4]) = pk;
      }
      // same-wave LDS write->read (DS in-order within a wave)
#pragma unroll
      for (int t = 0; t < 2; ++t) {
        const int nl = lane >> 2;
        const int colh = (lane & 3) * 8 + t * 32;
        int4 v = *(const int4*)(&sT[nl * 72 + colh]);
        *(int4*)(&C2p[(size_t)(n0 + wcol + j * 16 + nl) * M + m0 + wrow + colh]) = v;
      }
    }
  }
}

// Output GEMM: bf16 A (attn out), bf16 W, fp32 C = d_out
__global__ __launch_bounds__(256, 3)
void gemm_out(const unsigned short* __restrict__ A, const unsigned short* __restrict__ W,
              const float* __restrict__ bias, float* __restrict__ C,
              int M, int N, int K) {
  __shared__ __align__(16) unsigned short smem[8192];
  const int tid = threadIdx.x;
  const int wave = tid >> 6, lane = tid & 63, quad = lane >> 4, l16 = lane & 15;
  const int m0 = blockIdx.x * 128, n0 = blockIdx.y * 128;
  const int wrow = (wave >> 1) * 64, wcol = (wave & 1) * 64;

  f32x4 acc[4][4];
#pragma unroll
  for (int i = 0; i < 4; ++i)
#pragma unroll
    for (int j = 0; j < 4; ++j) acc[i][j] = (f32x4){0.f, 0.f, 0.f, 0.f};

  gemm_core(A, W, smem, smem + 4096, acc, K, m0, n0);

#pragma unroll
  for (int j = 0; j < 4; ++j) {
    const int col = n0 + wcol + j * 16 + l16;
    const float bv = bias[col];
#pragma unroll
    for (int i = 0; i < 4; ++i)
#pragma unroll
      for (int r = 0; r < 4; ++r) {
        const int row = m0 + wrow + i * 16 + quad * 4 + r;
        C[(size_t)row * N + col] = acc[i][j][r] + bv;
      }
  }
}

// ---------------------------------------------------------------------------
// Fused attention v8: v7 skeleton + double-buffered global_load_lds K/V
// staging (no ds_writes, latency hidden under compute), Q frags direct from
// global, standalone sP (stride 72). K/V LDS chunks are fragment-lane-linear
// (glds dest = uniform + lane*16B; read back the same way — m97 pattern).
// LDS: sP 18 KB + sK 2x8 KB + sVt 2x8 KB = 50 KB.
// ---------------------------------------------------------------------------
#define SEQ 2048
#define DMODEL 1024

__global__ __launch_bounds__(256, 2)
void attn_fused(const unsigned short* __restrict__ Q,
                const unsigned short* __restrict__ Km,
                const unsigned short* __restrict__ Vt,   // [1024][4096]
                unsigned short* __restrict__ O) {
  __shared__ __align__(16) unsigned short sK[2][4096];   // [buf][(key16*2+half)*512 + lane*8]
  __shared__ __align__(16) unsigned short sVt[2][4096];  // [buf][(hg*2+half)*512 + lane*8]
  __shared__ __align__(16) unsigned short sPb[4][2304];  // per-wave 32 x 72

  const int tid = threadIdx.x;
  const int wave = tid >> 6, lane = tid & 63, quad = lane >> 4, l16 = lane & 15;
  const int qt = blockIdx.x;        // 0..15
  const int bh = blockIdx.y;        // 0..31
  const int b = bh >> 4, h = bh & 15;
  const size_t qrow0 = (size_t)b * SEQ + qt * 128;
  const size_t kvrow0 = (size_t)b * SEQ;
  const int hcol = h * 64;
  const int bofs = b * SEQ;
  const int qw = wave * 32;

  // Q fragments once, direct from global
  bf16x8 qa[2][2];
#pragma unroll
  for (int qi = 0; qi < 2; ++qi)
#pragma unroll
    for (int ks = 0; ks < 2; ++ks) {
      int4 v = *(const int4*)(&Q[(qrow0 + qw + qi * 16 + l16) * DMODEL + hcol + ks * 32 + quad * 8]);
      qa[qi][ks] = *(bf16x8*)&v;
    }

  unsigned short* sP = sPb[wave];

  f32x4 acc[2][4];
#pragma unroll
  for (int qi = 0; qi < 2; ++qi)
#pragma unroll
    for (int hg = 0; hg < 4; ++hg) acc[qi][hg] = (f32x4){0.f, 0.f, 0.f, 0.f};
  float lsum[2] = {0.f, 0.f};

  const float SCL = 0.18033688011112042f;  // log2(e)/sqrt(64)

  // glds source/dest bases. Each wave DMAs key16-group `wave` of K and
  // hd16-group `wave` of V (2 halves each = 4 glds / wave / tile).
  const unsigned short* gK0 = Km + (kvrow0 + wave * 16 + l16) * DMODEL + hcol + quad * 8;
  const unsigned short* gV0 = Vt + (size_t)(hcol + wave * 16 + l16) * 4096 + bofs + quad * 8;
  unsigned short* lK0 = &sK[0][wave * 1024 + lane * 8];   // half adds 512
  unsigned short* lV0 = &sVt[0][wave * 1024 + lane * 8];

  // prologue: tile 0 -> buf 0
#pragma unroll
  for (int half = 0; half < 2; ++half) {
    glds16(gK0 + half * 32, lK0 + half * 512);
    glds16(gV0 + half * 32, lV0 + half * 512);
  }

  for (int kt = 0; kt < SEQ; kt += 64) {
    const int pb = (kt >> 6) & 1;
    __syncthreads();   // per-wave vmcnt(0) drain before s_barrier => tile kt landed

    // prefetch tile kt+64 into the other buffer (latency hidden under compute)
    const int ktn = (kt + 64 < SEQ) ? kt + 64 : kt;
    unsigned short* lKn = lK0 + (pb ^ 1) * 4096;
    unsigned short* lVn = lV0 + (pb ^ 1) * 4096;
#pragma unroll
    for (int half = 0; half < 2; ++half) {
      glds16(gK0 + (size_t)ktn * DMODEL + half * 32, lKn + half * 512);
      glds16(gV0 + ktn + half * 32, lVn + half * 512);
    }

    // S^T[key][q] = mfma(A=K frag, B=Q frag)
    f32x4 s[2][4];
#pragma unroll
    for (int qi = 0; qi < 2; ++qi)
#pragma unroll
      for (int kg = 0; kg < 4; ++kg) s[qi][kg] = (f32x4){0.f, 0.f, 0.f, 0.f};
#pragma unroll
    for (int kg = 0; kg < 4; ++kg) {
      bf16x8 kb0 = *(const bf16x8*)(&sK[pb][(kg * 2 + 0) * 512 + lane * 8]);
      bf16x8 kb1 = *(const bf16x8*)(&sK[pb][(kg * 2 + 1) * 512 + lane * 8]);
#pragma unroll
      for (int qi = 0; qi < 2; ++qi) {
        s[qi][kg] = __builtin_amdgcn_mfma_f32_16x16x32_bf16(kb0, qa[qi][0], s[qi][kg], 0, 0, 0);
        s[qi][kg] = __builtin_amdgcn_mfma_f32_16x16x32_bf16(kb1, qa[qi][1], s[qi][kg], 0, 0, 0);
      }
    }

    // exp (un-shifted), pack 4 consecutive keys -> one b64 write into q-major sP
#pragma unroll
    for (int qi = 0; qi < 2; ++qi)
#pragma unroll
      for (int kg = 0; kg < 4; ++kg) {
        float p0 = __builtin_amdgcn_exp2f(s[qi][kg][0] * SCL);
        float p1 = __builtin_amdgcn_exp2f(s[qi][kg][1] * SCL);
        float p2 = __builtin_amdgcn_exp2f(s[qi][kg][2] * SCL);
        float p3 = __builtin_amdgcn_exp2f(s[qi][kg][3] * SCL);
        lsum[qi] += (p0 + p1) + (p2 + p3);
        uint2 pk; pk.x = pack2(p0, p1); pk.y = pack2(p2, p3);
        *(uint2*)(&sP[(qi * 16 + l16) * 72 + kg * 16 + quad * 4]) = pk;
      }

    // O += P V  (same-wave LDS write->read, in-order)
#pragma unroll
    for (int ks = 0; ks < 2; ++ks) {
      bf16x8 pa[2], vb[4];
#pragma unroll
      for (int qi = 0; qi < 2; ++qi)
        pa[qi] = *(const bf16x8*)(&sP[(qi * 16 + l16) * 72 + ks * 32 + quad * 8]);
#pragma unroll
      for (int hg = 0; hg < 4; ++hg)
        vb[hg] = *(const bf16x8*)(&sVt[pb][(hg * 2 + ks) * 512 + lane * 8]);
#pragma unroll
      for (int qi = 0; qi < 2; ++qi)
#pragma unroll
        for (int hg = 0; hg < 4; ++hg)
          acc[qi][hg] = __builtin_amdgcn_mfma_f32_16x16x32_bf16(pa[qi], vb[hg], acc[qi][hg], 0, 0, 0);
    }
  }

  // row-sum: lane holds sum for q = qi*16+l16 over its quad's keys; reduce quads
#pragma unroll
  for (int qi = 0; qi < 2; ++qi) {
    float v = lsum[qi];
    v += __shfl_xor(v, 16, 64);
    v += __shfl_xor(v, 32, 64);
    lsum[qi] = v;
  }
  float linv[2][4];
#pragma unroll
  for (int qi = 0; qi < 2; ++qi)
#pragma unroll
    for (int r = 0; r < 4; ++r)
      linv[qi][r] = 1.0f / __shfl(lsum[qi], quad * 4 + r, 64);

#pragma unroll
  for (int qi = 0; qi < 2; ++qi)
#pragma unroll
    for (int hg = 0; hg < 4; ++hg)
#pragma unroll
      for (int r = 0; r < 4; ++r) {
        const size_t row = qrow0 + qw + qi * 16 + quad * 4 + r;
        O[row * DMODEL + hcol + hg * 16 + l16] = f2b(acc[qi][hg][r] * linv[qi][r]);
      }
}

// ---------------------------------------------------------------------------
extern "C" void kernel_launch(void* const* d_in, const int* in_sizes, int n_in,
                              void* d_out, int out_size, void* d_ws, size_t ws_size,
                              hipStream_t stream) {
  const float* xq = (const float*)d_in[0];
  const float* xv = (const float*)d_in[1];
  const float* xk = (const float*)d_in[2];
  const float* Wq = (const float*)d_in[3];
  const float* bq = (const float*)d_in[4];
  const float* Wk = (const float*)d_in[5];
  const float* bk = (const float*)d_in[6];
  const float* Wv = (const float*)d_in[7];
  const float* bv = (const float*)d_in[8];
  const float* Wo = (const float*)d_in[9];
  const float* bo = (const float*)d_in[10];
  float* out = (float*)d_out;

  const int S = 2048, D = 1024, M = 4096;
  const size_t MD = (size_t)M * D, DD = (size_t)D * D;
  unsigned short* P = (unsigned short*)d_ws;
  dim3 bb(256);
  dim3 gg(M / 128, D / 128);

  const size_t need = (3 * MD + 4 * DD + 3 * MD) * 2;
  if (ws_size >= need) {
    // fused path: all QKV in one z=3 launch (768 blocks = 3/CU)
    unsigned short* Ab = P;            // 3 act slices
    unsigned short* Wb = Ab + 3 * MD;  // 4 weight slices (q,k,v,o)
    unsigned short* Qw = Wb + 4 * DD;
    unsigned short* Kw = Qw + MD;
    unsigned short* Vtw = Kw + MD;
    unsigned short* Ao = Ab;           // attn out reuses act slice 0

    cvt_z<<<dim3((int)(MD / 8 / 256), 3), bb, 0, stream>>>(
        xq, xk, xv, xq, Ab, Ab + MD, Ab + 2 * MD, Ab, (int)(MD / 8));
    cvt_z<<<dim3((int)(DD / 8 / 256), 4), bb, 0, stream>>>(
        Wq, Wk, Wv, Wo, Wb, Wb + DD, Wb + 2 * DD, Wb + 3 * DD, (int)(DD / 8));
    gemm_qkv<<<dim3(M / 128, D / 128, 3), bb, 0, stream>>>(
        Ab, Ab + MD, Ab + 2 * MD, Wb, Wb + DD, Wb + 2 * DD,
        bq, bk, bv, Qw, Kw, Vtw, M, D, D, 0);
    attn_fused<<<dim3(S / 128, 32), bb, 0, stream>>>(Qw, Kw, Vtw, Ao);
    gemm_out<<<gg, bb, 0, stream>>>(Ao, Wb + 3 * DD, bo, out, M, D, D);
  } else {
    // sequential fallback (34 MB): act 8MB | W 2MB | Q 8 | K 8 | Vt 8
    unsigned short* Ab = P;
    unsigned short* Wb = Ab + MD;
    unsigned short* Qw = Wb + DD;
    unsigned short* Kw = Qw + MD;
    unsigned short* Vtw = Kw + MD;
    unsigned short* Ao = Ab;
    const int an = (int)(MD / 8), wn = (int)(DD / 8);

    cvt_z<<<dim3(an / 256, 1), bb, 0, stream>>>(xq, xq, xq, xq, Ab, Ab, Ab, Ab, an);
    cvt_z<<<dim3(wn / 256, 1), bb, 0, stream>>>(Wq, Wq, Wq, Wq, Wb, Wb, Wb, Wb, wn);
    gemm_qkv<<<dim3(M / 128, D / 128, 1), bb, 0, stream>>>(
        Ab, Ab, Ab, Wb, Wb, Wb, bq, bq, bq, Qw, Qw, Qw, M, D, D, 0);

    cvt_z<<<dim3(an / 256, 1), bb, 0, stream>>>(xk, xk, xk, xk, Ab, Ab, Ab, Ab, an);
    cvt_z<<<dim3(wn / 256, 1), bb, 0, stream>>>(Wk, Wk, Wk, Wk, Wb, Wb, Wb, Wb, wn);
    gemm_qkv<<<dim3(M / 128, D / 128, 1), bb, 0, stream>>>(
        Ab, Ab, Ab, Wb, Wb, Wb, bk, bk, bk, Kw, Kw, Kw, M, D, D, 0);

    cvt_z<<<dim3(an / 256, 1), bb, 0, stream>>>(xv, xv, xv, xv, Ab, Ab, Ab, Ab, an);
    cvt_z<<<dim3(wn / 256, 1), bb, 0, stream>>>(Wv, Wv, Wv, Wv, Wb, Wb, Wb, Wb, wn);
    gemm_qkv<<<dim3(M / 128, D / 128, 1), bb, 0, stream>>>(
        Ab, Ab, Ab, Wb, Wb, Wb, bv, bv, bv, Vtw, Vtw, Vtw, M, D, D, 2);

    attn_fused<<<dim3(S / 128, 32), bb, 0, stream>>>(Qw, Kw, Vtw, Ao);

    cvt_z<<<dim3(wn / 256, 1), bb, 0, stream>>>(Wo, Wo, Wo, Wo, Wb, Wb, Wb, Wb, wn);
    gemm_out<<<gg, bb, 0, stream>>>(Ao, Wb, bo, out, M, D, D);
  }
}

// Round 9
// 232.551 us; speedup vs baseline: 1.6562x; 1.0415x over previous
//
#include <hip/hip_runtime.h>

typedef __bf16 bf16x8 __attribute__((ext_vector_type(8)));
typedef float f32x4 __attribute__((ext_vector_type(4)));
typedef __attribute__((address_space(1))) const unsigned char ga_t;
typedef __attribute__((address_space(3))) unsigned char la_t;

static __device__ __forceinline__ unsigned short f2b(float f) {
  union { float f; unsigned int i; } c; c.f = f;
  unsigned int r = c.i + 0x7FFFu + ((c.i >> 16) & 1u);
  return (unsigned short)(r >> 16);
}
// gfx950 HW packed f32->bf16 (RNE), low=a high=b
static __device__ __forceinline__ unsigned int pack2(float a, float b) {
  unsigned int r;
  asm("v_cvt_pk_bf16_f32 %0, %1, %2" : "=v"(r) : "v"(a), "v"(b));
  return r;
}
static __device__ __forceinline__ int4 ld8f_cvt(const float* __restrict__ p) {
  float4 a = *(const float4*)p;
  float4 b = *(const float4*)(p + 4);
  uint4 u;
  u.x = pack2(a.x, a.y); u.y = pack2(a.z, a.w);
  u.z = pack2(b.x, b.y); u.w = pack2(b.z, b.w);
  return *(int4*)&u;
}
static __device__ __forceinline__ void glds16(const unsigned short* g, unsigned short* l) {
  __builtin_amdgcn_global_load_lds((ga_t*)g, (la_t*)l, 16, 0, 0);
}

// fp32 -> bf16 convert, up to 4 streams via blockIdx.y
__global__ __launch_bounds__(256)
void cvt_z(const float* __restrict__ s0, const float* __restrict__ s1,
           const float* __restrict__ s2, const float* __restrict__ s3,
           unsigned short* d0, unsigned short* d1,
           unsigned short* d2, unsigned short* d3, int n8) {
  const int z = blockIdx.y;
  const float* s = z == 0 ? s0 : z == 1 ? s1 : z == 2 ? s2 : s3;
  unsigned short* d = z == 0 ? d0 : z == 1 ? d1 : z == 2 ? d2 : d3;
  int idx = blockIdx.x * 256 + threadIdx.x;
  if (idx < n8) *(int4*)(d + (size_t)idx * 8) = ld8f_cvt(s + (size_t)idx * 8);
}

// ---------------------------------------------------------------------------
// Shared GEMM core: 128x128 tile, BK=32, global_load_lds width-16 staging
// into UNPADDED 128x32 LDS tiles (lane-linear; glds requires it).
// ---------------------------------------------------------------------------
static __device__ __forceinline__ void gemm_core(
    const unsigned short* __restrict__ A, const unsigned short* __restrict__ W,
    unsigned short* sA, unsigned short* sB, f32x4 acc[4][4],
    int K, int m0, int n0) {
  const int tid = threadIdx.x;
  const int wave = tid >> 6, lane = tid & 63, quad = lane >> 4, l16 = lane & 15;
  const int wrow = (wave >> 1) * 64, wcol = (wave & 1) * 64;
  const int r = tid >> 2, c8 = (tid & 3) * 8;

  const unsigned short* gA0 = A + (size_t)(m0 + r) * K + c8;
  const unsigned short* gA1 = gA0 + (size_t)64 * K;
  const unsigned short* gB0 = W + (size_t)(n0 + r) * K + c8;
  const unsigned short* gB1 = gB0 + (size_t)64 * K;
  unsigned short* lA0 = sA + tid * 8;
  unsigned short* lA1 = lA0 + 2048;
  unsigned short* lB0 = sB + tid * 8;
  unsigned short* lB1 = lB0 + 2048;

  for (int k0 = 0; k0 < K; k0 += 32) {
    __syncthreads();
    glds16(gA0 + k0, lA0);
    glds16(gA1 + k0, lA1);
    glds16(gB0 + k0, lB0);
    glds16(gB1 + k0, lB1);
    __syncthreads();

    bf16x8 af[4], bfv[4];
#pragma unroll
    for (int i = 0; i < 4; ++i)
      af[i] = *(const bf16x8*)(&sA[(wrow + i * 16 + l16) * 32 + quad * 8]);
#pragma unroll
    for (int j = 0; j < 4; ++j)
      bfv[j] = *(const bf16x8*)(&sB[(wcol + j * 16 + l16) * 32 + quad * 8]);
#pragma unroll
    for (int i = 0; i < 4; ++i)
#pragma unroll
      for (int j = 0; j < 4; ++j)
        acc[i][j] = __builtin_amdgcn_mfma_f32_16x16x32_bf16(af[i], bfv[j], acc[i][j], 0, 0, 0);
  }
}

// QKV fused GEMM: z selects projection. z<2 -> bf16 C row-major (z==0 scaled
// by q0scale = log2(e)/sqrt(HD), folded softmax scale — Q only feeds attn);
// z==2 -> bf16 C^T (V transposed for attention), via per-wave LDS transpose.
__global__ __launch_bounds__(256, 3)
void gemm_qkv(const unsigned short* __restrict__ A0p, const unsigned short* __restrict__ A1p,
              const unsigned short* __restrict__ A2p,
              const unsigned short* __restrict__ W0p, const unsigned short* __restrict__ W1p,
              const unsigned short* __restrict__ W2p,
              const float* __restrict__ b0p, const float* __restrict__ b1p,
              const float* __restrict__ b2p,
              unsigned short* __restrict__ C0p, unsigned short* __restrict__ C1p,
              unsigned short* __restrict__ C2p,
              int M, int N, int K, int zbase, float q0scale) {
  __shared__ __align__(16) unsigned short smem[8192];  // sA | sB, 16 KB
  const int z = blockIdx.z + zbase;
  const unsigned short* A = z == 0 ? A0p : z == 1 ? A1p : A2p;
  const unsigned short* W = z == 0 ? W0p : z == 1 ? W1p : W2p;
  const float* bias = z == 0 ? b0p : z == 1 ? b1p : b2p;

  const int tid = threadIdx.x;
  const int wave = tid >> 6, lane = tid & 63, quad = lane >> 4, l16 = lane & 15;
  const int m0 = blockIdx.x * 128, n0 = blockIdx.y * 128;
  const int wrow = (wave >> 1) * 64, wcol = (wave & 1) * 64;

  f32x4 acc[4][4];
#pragma unroll
  for (int i = 0; i < 4; ++i)
#pragma unroll
    for (int j = 0; j < 4; ++j) acc[i][j] = (f32x4){0.f, 0.f, 0.f, 0.f};

  gemm_core(A, W, smem, smem + 4096, acc, K, m0, n0);

  if (z < 2) {
    unsigned short* C = z == 0 ? C0p : C1p;
    const float qs = (z == 0) ? q0scale : 1.0f;
#pragma unroll
    for (int j = 0; j < 4; ++j) {
      const int col = n0 + wcol + j * 16 + l16;
      const float bv = bias[col];
#pragma unroll
      for (int i = 0; i < 4; ++i)
#pragma unroll
        for (int r = 0; r < 4; ++r) {
          const int row = m0 + wrow + i * 16 + quad * 4 + r;
          C[(size_t)row * N + col] = f2b((acc[i][j][r] + bv) * qs);
        }
    }
  } else {
    // transpose epilogue: reuse smem (per-wave 16x72 chunk), 4 passes of 16 cols
    __syncthreads();  // all waves done with frag reads before clobbering smem
    unsigned short* sT = smem + wave * 1152;
#pragma unroll
    for (int j = 0; j < 4; ++j) {
      const float bv = bias[n0 + wcol + j * 16 + l16];
#pragma unroll
      for (int i = 0; i < 4; ++i) {
        uint2 pk;
        pk.x = pack2(acc[i][j][0] + bv, acc[i][j][1] + bv);
        pk.y = pack2(acc[i][j][2] + bv, acc[i][j][3] + bv);
        *(uint2*)(&sT[l16 * 72 + i * 16 + quad * 4]) = pk;
      }
      // same-wave LDS write->read (DS in-order within a wave)
#pragma unroll
      for (int t = 0; t < 2; ++t) {
        const int nl = lane >> 2;
        const int colh = (lane & 3) * 8 + t * 32;
        int4 v = *(const int4*)(&sT[nl * 72 + colh]);
        *(int4*)(&C2p[(size_t)(n0 + wcol + j * 16 + nl) * M + m0 + wrow + colh]) = v;
      }
    }
  }
}

// Output GEMM: bf16 A (attn out), bf16 W, fp32 C = d_out
__global__ __launch_bounds__(256, 3)
void gemm_out(const unsigned short* __restrict__ A, const unsigned short* __restrict__ W,
              const float* __restrict__ bias, float* __restrict__ C,
              int M, int N, int K) {
  __shared__ __align__(16) unsigned short smem[8192];
  const int tid = threadIdx.x;
  const int wave = tid >> 6, lane = tid & 63, quad = lane >> 4, l16 = lane & 15;
  const int m0 = blockIdx.x * 128, n0 = blockIdx.y * 128;
  const int wrow = (wave >> 1) * 64, wcol = (wave & 1) * 64;

  f32x4 acc[4][4];
#pragma unroll
  for (int i = 0; i < 4; ++i)
#pragma unroll
    for (int j = 0; j < 4; ++j) acc[i][j] = (f32x4){0.f, 0.f, 0.f, 0.f};

  gemm_core(A, W, smem, smem + 4096, acc, K, m0, n0);

#pragma unroll
  for (int j = 0; j < 4; ++j) {
    const int col = n0 + wcol + j * 16 + l16;
    const float bv = bias[col];
#pragma unroll
    for (int i = 0; i < 4; ++i)
#pragma unroll
      for (int r = 0; r < 4; ++r) {
        const int row = m0 + wrow + i * 16 + quad * 4 + r;
        C[(size_t)row * N + col] = acc[i][j][r] + bv;
      }
  }
}

// ---------------------------------------------------------------------------
// Fused attention v9 = v8 + softmax VALU cuts:
//  - Q pre-scaled by log2(e)/8 in projection (no per-element mul here)
//  - v_cvt_pk_bf16_f32 for P packing (1 op/pair vs ~10)
//  - row-sums via MFMA ones-trick (lacc): no VALU adds, no end shuffles;
//    lacc C-layout rows align exactly with O-write rows.
// Double-buffered glds K/V staging, Q frags direct from global, sP stride 72.
// ---------------------------------------------------------------------------
#define SEQ 2048
#define DMODEL 1024

__global__ __launch_bounds__(256, 2)
void attn_fused(const unsigned short* __restrict__ Q,
                const unsigned short* __restrict__ Km,
                const unsigned short* __restrict__ Vt,   // [1024][4096]
                unsigned short* __restrict__ O) {
  __shared__ __align__(16) unsigned short sK[2][4096];   // [buf][(key16*2+half)*512 + lane*8]
  __shared__ __align__(16) unsigned short sVt[2][4096];  // [buf][(hg*2+half)*512 + lane*8]
  __shared__ __align__(16) unsigned short sPb[4][2304];  // per-wave 32 x 72

  const int tid = threadIdx.x;
  const int wave = tid >> 6, lane = tid & 63, quad = lane >> 4, l16 = lane & 15;
  const int qt = blockIdx.x;        // 0..15
  const int bh = blockIdx.y;        // 0..31
  const int b = bh >> 4, h = bh & 15;
  const size_t qrow0 = (size_t)b * SEQ + qt * 128;
  const size_t kvrow0 = (size_t)b * SEQ;
  const int hcol = h * 64;
  const int bofs = b * SEQ;
  const int qw = wave * 32;

  // Q fragments once, direct from global (pre-scaled by log2(e)/8)
  bf16x8 qa[2][2];
#pragma unroll
  for (int qi = 0; qi < 2; ++qi)
#pragma unroll
    for (int ks = 0; ks < 2; ++ks) {
      int4 v = *(const int4*)(&Q[(qrow0 + qw + qi * 16 + l16) * DMODEL + hcol + ks * 32 + quad * 8]);
      qa[qi][ks] = *(bf16x8*)&v;
    }

  // all-ones B fragment for the row-sum MFMA
  bf16x8 ones;
#pragma unroll
  for (int i = 0; i < 8; ++i) ones[i] = (__bf16)1.0f;

  unsigned short* sP = sPb[wave];

  f32x4 acc[2][4], lacc[2];
#pragma unroll
  for (int qi = 0; qi < 2; ++qi) {
    lacc[qi] = (f32x4){0.f, 0.f, 0.f, 0.f};
#pragma unroll
    for (int hg = 0; hg < 4; ++hg) acc[qi][hg] = (f32x4){0.f, 0.f, 0.f, 0.f};
  }

  // glds source/dest bases. Each wave DMAs key16-group `wave` of K and
  // hd16-group `wave` of V (2 halves each = 4 glds / wave / tile).
  const unsigned short* gK0 = Km + (kvrow0 + wave * 16 + l16) * DMODEL + hcol + quad * 8;
  const unsigned short* gV0 = Vt + (size_t)(hcol + wave * 16 + l16) * 4096 + bofs + quad * 8;
  unsigned short* lK0 = &sK[0][wave * 1024 + lane * 8];   // half adds 512
  unsigned short* lV0 = &sVt[0][wave * 1024 + lane * 8];

  // prologue: tile 0 -> buf 0
#pragma unroll
  for (int half = 0; half < 2; ++half) {
    glds16(gK0 + half * 32, lK0 + half * 512);
    glds16(gV0 + half * 32, lV0 + half * 512);
  }

  for (int kt = 0; kt < SEQ; kt += 64) {
    const int pb = (kt >> 6) & 1;
    __syncthreads();   // per-wave vmcnt(0) drain before s_barrier => tile kt landed

    // prefetch tile kt+64 into the other buffer (latency hidden under compute)
    const int ktn = (kt + 64 < SEQ) ? kt + 64 : kt;
    unsigned short* lKn = lK0 + (pb ^ 1) * 4096;
    unsigned short* lVn = lV0 + (pb ^ 1) * 4096;
#pragma unroll
    for (int half = 0; half < 2; ++half) {
      glds16(gK0 + (size_t)ktn * DMODEL + half * 32, lKn + half * 512);
      glds16(gV0 + ktn + half * 32, lVn + half * 512);
    }

    // S^T[key][q] = mfma(A=K frag, B=Q frag)
    f32x4 s[2][4];
#pragma unroll
    for (int qi = 0; qi < 2; ++qi)
#pragma unroll
      for (int kg = 0; kg < 4; ++kg) s[qi][kg] = (f32x4){0.f, 0.f, 0.f, 0.f};
#pragma unroll
    for (int kg = 0; kg < 4; ++kg) {
      bf16x8 kb0 = *(const bf16x8*)(&sK[pb][(kg * 2 + 0) * 512 + lane * 8]);
      bf16x8 kb1 = *(const bf16x8*)(&sK[pb][(kg * 2 + 1) * 512 + lane * 8]);
#pragma unroll
      for (int qi = 0; qi < 2; ++qi) {
        s[qi][kg] = __builtin_amdgcn_mfma_f32_16x16x32_bf16(kb0, qa[qi][0], s[qi][kg], 0, 0, 0);
        s[qi][kg] = __builtin_amdgcn_mfma_f32_16x16x32_bf16(kb1, qa[qi][1], s[qi][kg], 0, 0, 0);
      }
    }

    // exp2 (scale pre-folded), HW packed cvt -> b64 writes into q-major sP
#pragma unroll
    for (int qi = 0; qi < 2; ++qi)
#pragma unroll
      for (int kg = 0; kg < 4; ++kg) {
        float p0 = __builtin_amdgcn_exp2f(s[qi][kg][0]);
        float p1 = __builtin_amdgcn_exp2f(s[qi][kg][1]);
        float p2 = __builtin_amdgcn_exp2f(s[qi][kg][2]);
        float p3 = __builtin_amdgcn_exp2f(s[qi][kg][3]);
        uint2 pk; pk.x = pack2(p0, p1); pk.y = pack2(p2, p3);
        *(uint2*)(&sP[(qi * 16 + l16) * 72 + kg * 16 + quad * 4]) = pk;
      }

    // O += P V ; row-sums += P * ones  (same-wave LDS write->read, in-order)
#pragma unroll
    for (int ks = 0; ks < 2; ++ks) {
      bf16x8 pa[2], vb[4];
#pragma unroll
      for (int qi = 0; qi < 2; ++qi)
        pa[qi] = *(const bf16x8*)(&sP[(qi * 16 + l16) * 72 + ks * 32 + quad * 8]);
#pragma unroll
      for (int hg = 0; hg < 4; ++hg)
        vb[hg] = *(const bf16x8*)(&sVt[pb][(hg * 2 + ks) * 512 + lane * 8]);
#pragma unroll
      for (int qi = 0; qi < 2; ++qi) {
#pragma unroll
        for (int hg = 0; hg < 4; ++hg)
          acc[qi][hg] = __builtin_amdgcn_mfma_f32_16x16x32_bf16(pa[qi], vb[hg], acc[qi][hg], 0, 0, 0);
        lacc[qi] = __builtin_amdgcn_mfma_f32_16x16x32_bf16(pa[qi], ones, lacc[qi], 0, 0, 0);
      }
    }
  }

  // lacc[qi][r] = rowsum for row quad*4+r (same row the O-write uses)
#pragma unroll
  for (int qi = 0; qi < 2; ++qi)
#pragma unroll
    for (int r = 0; r < 4; ++r) {
      const float linv = 1.0f / lacc[qi][r];
      const size_t row = qrow0 + qw + qi * 16 + quad * 4 + r;
#pragma unroll
      for (int hg = 0; hg < 4; ++hg)
        O[row * DMODEL + hcol + hg * 16 + l16] = f2b(acc[qi][hg][r] * linv);
    }
}

// ---------------------------------------------------------------------------
extern "C" void kernel_launch(void* const* d_in, const int* in_sizes, int n_in,
                              void* d_out, int out_size, void* d_ws, size_t ws_size,
                              hipStream_t stream) {
  const float* xq = (const float*)d_in[0];
  const float* xv = (const float*)d_in[1];
  const float* xk = (const float*)d_in[2];
  const float* Wq = (const float*)d_in[3];
  const float* bq = (const float*)d_in[4];
  const float* Wk = (const float*)d_in[5];
  const float* bk = (const float*)d_in[6];
  const float* Wv = (const float*)d_in[7];
  const float* bv = (const float*)d_in[8];
  const float* Wo = (const float*)d_in[9];
  const float* bo = (const float*)d_in[10];
  float* out = (float*)d_out;

  const int S = 2048, D = 1024, M = 4096;
  const size_t MD = (size_t)M * D, DD = (size_t)D * D;
  const float SCL = 0.18033688011112042f;  // log2(e)/sqrt(64)
  unsigned short* P = (unsigned short*)d_ws;
  dim3 bb(256);
  dim3 gg(M / 128, D / 128);

  const size_t need = (3 * MD + 4 * DD + 3 * MD) * 2;
  if (ws_size >= need) {
    // fused path: all QKV in one z=3 launch (768 blocks = 3/CU)
    unsigned short* Ab = P;            // 3 act slices
    unsigned short* Wb = Ab + 3 * MD;  // 4 weight slices (q,k,v,o)
    unsigned short* Qw = Wb + 4 * DD;
    unsigned short* Kw = Qw + MD;
    unsigned short* Vtw = Kw + MD;
    unsigned short* Ao = Ab;           // attn out reuses act slice 0

    cvt_z<<<dim3((int)(MD / 8 / 256), 3), bb, 0, stream>>>(
        xq, xk, xv, xq, Ab, Ab + MD, Ab + 2 * MD, Ab, (int)(MD / 8));
    cvt_z<<<dim3((int)(DD / 8 / 256), 4), bb, 0, stream>>>(
        Wq, Wk, Wv, Wo, Wb, Wb + DD, Wb + 2 * DD, Wb + 3 * DD, (int)(DD / 8));
    gemm_qkv<<<dim3(M / 128, D / 128, 3), bb, 0, stream>>>(
        Ab, Ab + MD, Ab + 2 * MD, Wb, Wb + DD, Wb + 2 * DD,
        bq, bk, bv, Qw, Kw, Vtw, M, D, D, 0, SCL);
    attn_fused<<<dim3(S / 128, 32), bb, 0, stream>>>(Qw, Kw, Vtw, Ao);
    gemm_out<<<gg, bb, 0, stream>>>(Ao, Wb + 3 * DD, bo, out, M, D, D);
  } else {
    // sequential fallback (34 MB): act 8MB | W 2MB | Q 8 | K 8 | Vt 8
    unsigned short* Ab = P;
    unsigned short* Wb = Ab + MD;
    unsigned short* Qw = Wb + DD;
    unsigned short* Kw = Qw + MD;
    unsigned short* Vtw = Kw + MD;
    unsigned short* Ao = Ab;
    const int an = (int)(MD / 8), wn = (int)(DD / 8);

    cvt_z<<<dim3(an / 256, 1), bb, 0, stream>>>(xq, xq, xq, xq, Ab, Ab, Ab, Ab, an);
    cvt_z<<<dim3(wn / 256, 1), bb, 0, stream>>>(Wq, Wq, Wq, Wq, Wb, Wb, Wb, Wb, wn);
    gemm_qkv<<<dim3(M / 128, D / 128, 1), bb, 0, stream>>>(
        Ab, Ab, Ab, Wb, Wb, Wb, bq, bq, bq, Qw, Qw, Qw, M, D, D, 0, SCL);

    cvt_z<<<dim3(an / 256, 1), bb, 0, stream>>>(xk, xk, xk, xk, Ab, Ab, Ab, Ab, an);
    cvt_z<<<dim3(wn / 256, 1), bb, 0, stream>>>(Wk, Wk, Wk, Wk, Wb, Wb, Wb, Wb, wn);
    gemm_qkv<<<dim3(M / 128, D / 128, 1), bb, 0, stream>>>(
        Ab, Ab, Ab, Wb, Wb, Wb, bk, bk, bk, Kw, Kw, Kw, M, D, D, 0, 1.0f);

    cvt_z<<<dim3(an / 256, 1), bb, 0, stream>>>(xv, xv, xv, xv, Ab, Ab, Ab, Ab, an);
    cvt_z<<<dim3(wn / 256, 1), bb, 0, stream>>>(Wv, Wv, Wv, Wv, Wb, Wb, Wb, Wb, wn);
    gemm_qkv<<<dim3(M / 128, D / 128, 1), bb, 0, stream>>>(
        Ab, Ab, Ab, Wb, Wb, Wb, bv, bv, bv, Vtw, Vtw, Vtw, M, D, D, 2, 1.0f);

    attn_fused<<<dim3(S / 128, 32), bb, 0, stream>>>(Qw, Kw, Vtw, Ao);

    cvt_z<<<dim3(wn / 256, 1), bb, 0, stream>>>(Wo, Wo, Wo, Wo, Wb, Wb, Wb, Wb, wn);
    gemm_out<<<gg, bb, 0, stream>>>(Ao, Wb, bo, out, M, D, D);
  }
}